// Round 26
// baseline (156.500 us; speedup 1.0000x reference)
//
#include <hip/hip_runtime.h>

#define HID 256
#define FIN 128
#define NGRAPH 64
#define NEG 0.2f
#define DEGSCALE 16384.0f
#define GTILES 16

typedef __attribute__((ext_vector_type(8))) short short8;
typedef __attribute__((ext_vector_type(4))) float f32x4;

__device__ __forceinline__ float lrelu(float v) { return v >= 0.f ? v : NEG * v; }

__device__ __forceinline__ unsigned short f2bf(float f) {
    union { float f; unsigned u; } c; c.f = f;
    unsigned u = c.u;
    unsigned r = (u + 0x7FFFu + ((u >> 16) & 1u)) >> 16;   // RNE
    return (unsigned short)r;
}
__device__ __forceinline__ float bf2f(unsigned short u) {
    union { unsigned u; float f; } c; c.u = ((unsigned)u) << 16; return c.f;
}

// ---------------- merged setup + count ----------------
// pk pre-zeroed by hipMemsetAsync. Blocks [0, sblocks) convert x and W1;
// blocks [sblocks, ...) run the per-edge packed atomic count (independent work,
// now overlapped in one dispatch). Self-loop +1.0 deg is added in k_scanA2.

__global__ void k_setupcount(const float* __restrict__ x, unsigned short* __restrict__ xbf,
                             const float* __restrict__ W1, unsigned short* __restrict__ w1t,
                             const int* __restrict__ col, const float* __restrict__ ew,
                             unsigned* __restrict__ pk, unsigned char* __restrict__ seq,
                             int N, int E, int sblocks) {
    int t = threadIdx.x;
    if ((int)blockIdx.x < sblocks) {
        int i = blockIdx.x * 256 + t;
        int n4 = N * (FIN / 4);
        if (i < n4) {
            float4 v = ((const float4*)x)[i];
            ushort4 o; o.x = f2bf(v.x); o.y = f2bf(v.y); o.z = f2bf(v.z); o.w = f2bf(v.w);
            ((ushort4*)xbf)[i] = o;
        }
        if (i < FIN * HID) {
            int k = i >> 8;
            int n = i & 255;
            w1t[(size_t)n * FIN + k] = f2bf(W1[(size_t)k * HID + n]);
        }
    } else {
        int e = (blockIdx.x - sblocks) * 256 + t;
        if (e < E) {
            unsigned fixw = (unsigned)(ew[e] * DEGSCALE + 0.5f);
            unsigned old = atomicAdd(&pk[col[e]], (1u << 24) | fixw);
            seq[e] = (unsigned char)(old >> 24);
        }
    }
}

// ---------------- fused dinv + scanA (self-loop deg folded in) ----------------

__global__ void k_scanA2(unsigned* __restrict__ pk, int* __restrict__ off,
                         int* __restrict__ bsum, int N) {
    __shared__ int buf[256];
    int t = threadIdx.x, i = blockIdx.x * 256 + t;
    unsigned p = (i < N) ? pk[i] : 0u;
    buf[t] = (int)(p >> 24);
    __syncthreads();
    for (int s = 1; s < 256; s <<= 1) {
        int a = (t >= s) ? buf[t - s] : 0;
        __syncthreads();
        buf[t] += a;
        __syncthreads();
    }
    if (i < N) {
        off[i + 1] = buf[t];
        float dg = (float)(p & 0xFFFFFFu) * (1.0f / DEGSCALE) + 1.0f;  // +1.0 self-loop
        float dv = rsqrtf(dg);
        union { float f; unsigned u; } c; c.f = dv;
        pk[i] = c.u;
    }
    if (t == 255) bsum[blockIdx.x] = buf[255];
}

// ---------------- fused scanB + scanC + starts (validated round 23) ----------------

__global__ void k_scanC2(int* __restrict__ off, const int* __restrict__ bsum, int N, int nb,
                         const int* __restrict__ batch, int* __restrict__ starts) {
    __shared__ int sb[256];
    int t = threadIdx.x;
    sb[t] = (t < nb) ? bsum[t] : 0;
    __syncthreads();
    for (int s = 1; s < 256; s <<= 1) {
        int a = (t >= s) ? sb[t - s] : 0;
        __syncthreads();
        sb[t] += a;
        __syncthreads();
    }
    int i = blockIdx.x * 256 + t;
    if (i < N && blockIdx.x > 0) off[i + 1] += sb[blockIdx.x - 1];
    if (i == 0) off[0] = 0;
    if (blockIdx.x == 0 && t <= NGRAPH) {
        int g = t;
        int lo = 0, hi = N;
        while (lo < hi) {
            int mid = (lo + hi) >> 1;
            if (batch[mid] < g) lo = mid + 1; else hi = mid;
        }
        starts[g] = lo;
    }
}

// ---------------- fill (validated round 22) ----------------

__global__ void k_fill(const int* __restrict__ row, const int* __restrict__ col,
                       const float* __restrict__ ew, const unsigned* __restrict__ dinvu,
                       const int* __restrict__ off, const unsigned char* __restrict__ seq,
                       unsigned* __restrict__ epack, int E) {
    int e = blockIdx.x * 256 + threadIdx.x;
    if (e >= E) return;
    int r = row[e], c = col[e];
    union { unsigned u; float f; } dr, dc;
    dr.u = dinvu[r]; dc.u = dinvu[c];
    float w = dr.f * ew[e] * dc.f;
    int s = off[c] + (int)seq[e];
    epack[s] = ((unsigned)f2bf(w) << 16) | (unsigned)r;
}

// ---------------- gather v4 (validated round 24): 4-way unroll ----------------

__global__ __launch_bounds__(256) void k_gather(const int* __restrict__ off,
        const unsigned* __restrict__ epack,
        const unsigned short* __restrict__ xbf, const unsigned* __restrict__ dinvu,
        unsigned short* __restrict__ xaggbf, int N) {
    int n = blockIdx.x * 8 + (threadIdx.x >> 5);
    int l = threadIdx.x & 31;
    if (n >= N) return;
    const ushort4* x4 = (const ushort4*)xbf;
    union { unsigned u; float f; } dc; dc.u = dinvu[n];
    float s2 = dc.f * dc.f;
    ushort4 xv = x4[(size_t)n * 32 + l];
    float ax = s2 * bf2f(xv.x), ay = s2 * bf2f(xv.y), az = s2 * bf2f(xv.z), aw = s2 * bf2f(xv.w);
    float bx = 0.f, by = 0.f, bz = 0.f, bw = 0.f;
    float cx = 0.f, cy = 0.f, cz = 0.f, cw = 0.f;
    float dx = 0.f, dy = 0.f, dz = 0.f, dw = 0.f;
    int s0 = off[n], s1 = off[n + 1];
    int s = s0;
    for (; s + 4 <= s1; s += 4) {
        unsigned p0 = epack[s],     p1 = epack[s + 1];
        unsigned p2 = epack[s + 2], p3 = epack[s + 3];
        float w0 = bf2f((unsigned short)(p0 >> 16));
        float w1 = bf2f((unsigned short)(p1 >> 16));
        float w2 = bf2f((unsigned short)(p2 >> 16));
        float w3 = bf2f((unsigned short)(p3 >> 16));
        ushort4 v0 = x4[(size_t)(p0 & 0xFFFFu) * 32 + l];
        ushort4 v1 = x4[(size_t)(p1 & 0xFFFFu) * 32 + l];
        ushort4 v2 = x4[(size_t)(p2 & 0xFFFFu) * 32 + l];
        ushort4 v3 = x4[(size_t)(p3 & 0xFFFFu) * 32 + l];
        ax += w0 * bf2f(v0.x); ay += w0 * bf2f(v0.y); az += w0 * bf2f(v0.z); aw += w0 * bf2f(v0.w);
        bx += w1 * bf2f(v1.x); by += w1 * bf2f(v1.y); bz += w1 * bf2f(v1.z); bw += w1 * bf2f(v1.w);
        cx += w2 * bf2f(v2.x); cy += w2 * bf2f(v2.y); cz += w2 * bf2f(v2.z); cw += w2 * bf2f(v2.w);
        dx += w3 * bf2f(v3.x); dy += w3 * bf2f(v3.y); dz += w3 * bf2f(v3.z); dw += w3 * bf2f(v3.w);
    }
    for (; s < s1; ++s) {
        unsigned p0 = epack[s];
        float w0 = bf2f((unsigned short)(p0 >> 16));
        ushort4 v0 = x4[(size_t)(p0 & 0xFFFFu) * 32 + l];
        ax += w0 * bf2f(v0.x); ay += w0 * bf2f(v0.y); az += w0 * bf2f(v0.z); aw += w0 * bf2f(v0.w);
    }
    ushort4 st;
    st.x = f2bf((ax + bx) + (cx + dx));
    st.y = f2bf((ay + by) + (cy + dy));
    st.z = f2bf((az + bz) + (cz + dz));
    st.w = f2bf((aw + bw) + (cw + dw));
    ((ushort4*)xaggbf)[(size_t)n * 32 + l] = st;
}

// ---------------- gpool v10 (validated round 24) ----------------

__global__ __launch_bounds__(256) void k_gpool(
        const unsigned short* __restrict__ xaggbf, const unsigned short* __restrict__ w1t,
        const float* __restrict__ b1, const int* __restrict__ starts,
        float* __restrict__ partial) {
    __shared__ float red[4][128];
    const int tile = blockIdx.x;
    const int g = blockIdx.y;
    const int t = threadIdx.x;
    const int w = t >> 6;
    const int l = t & 63;
    const int col = l & 15;
    const int koff = (l >> 4) * 8;
    const int gs = starts[g], ge = starts[g + 1];
    const int n0 = gs + tile * 64;
    float* pbase = partial + ((size_t)g * GTILES + tile) * HID;
    if (n0 >= ge) {
        pbase[t] = 0.f;
        return;
    }
    int rbase = n0 + w * 16 + col;
    int rclamp = rbase < ge ? rbase : ge - 1;
    short8 a[4];
    #pragma unroll
    for (int kt = 0; kt < 4; ++kt)
        a[kt] = *(const short8*)(xaggbf + (size_t)rclamp * FIN + kt * 32 + koff);
    const int rowbase = n0 + w * 16 + (l >> 4) * 4;
    #pragma unroll
    for (int half = 0; half < 2; ++half) {
        const int col0 = half * 128;
        f32x4 acc[8];
        #pragma unroll
        for (int c = 0; c < 8; ++c) acc[c] = (f32x4){0.f, 0.f, 0.f, 0.f};
        #pragma unroll
        for (int kt = 0; kt < 4; ++kt) {
            short8 b[8];
            #pragma unroll
            for (int c = 0; c < 8; ++c)
                b[c] = *(const short8*)(w1t + (size_t)(col0 + c * 16 + col) * FIN + kt * 32 + koff);
            #pragma unroll
            for (int c = 0; c < 8; ++c)
                acc[c] = __builtin_amdgcn_mfma_f32_16x16x32_bf16(a[kt], b[c], acc[c], 0, 0, 0);
        }
        if (half) __syncthreads();
        #pragma unroll
        for (int c = 0; c < 8; ++c) {
            float bias = b1[col0 + c * 16 + col];
            float s = 0.f;
            #pragma unroll
            for (int r = 0; r < 4; ++r)
                if (rowbase + r < ge) s += lrelu(acc[c][r] + bias);
            s += __shfl_xor(s, 16);
            s += __shfl_xor(s, 32);
            if (l < 16) red[w][c * 16 + l] = s;
        }
        __syncthreads();
        if (t < 128) pbase[col0 + t] = red[0][t] + red[1][t] + red[2][t] + red[3][t];
    }
}

// ---------------- head (validated round 21) ----------------

__global__ void k_head(const float* __restrict__ partial, const int* __restrict__ starts,
                       const float* __restrict__ emb, const int* __restrict__ labels,
                       const float* __restrict__ W2, const float* __restrict__ b2,
                       const float* __restrict__ W3, const float* __restrict__ b3,
                       float* __restrict__ out) {
    __shared__ float z[384];
    __shared__ float red[256];
    int g = blockIdx.x, t = threadIdx.x;
    int cnt = starts[g + 1] - starts[g];
    float inv = 1.0f / (float)(cnt < 1 ? 1 : cnt);
    float s = 0.f;
    #pragma unroll
    for (int i = 0; i < GTILES; ++i)
        s += partial[((size_t)g * GTILES + i) * HID + t];
    z[t] = s * inv;
    if (t < 128) z[HID + t] = emb[labels[g] * 128 + t];
    __syncthreads();
    float acc = b2[t];
    for (int k = 0; k < 384; ++k) acc += z[k] * W2[k * HID + t];
    red[t] = lrelu(acc) * W3[t];
    __syncthreads();
    for (int ss = 128; ss > 0; ss >>= 1) {
        if (t < ss) red[t] += red[t + ss];
        __syncthreads();
    }
    if (t == 0) out[g] = red[0] + b3[0];
}

extern "C" void kernel_launch(void* const* d_in, const int* in_sizes, int n_in,
                              void* d_out, int out_size, void* d_ws, size_t ws_size,
                              hipStream_t stream) {
    (void)n_in; (void)out_size; (void)ws_size;
    const float* x      = (const float*)d_in[0];
    const int*   ei     = (const int*)d_in[1];
    const float* ew     = (const float*)d_in[2];
    const int*   batch  = (const int*)d_in[3];
    const int*   labels = (const int*)d_in[4];
    const float* W1     = (const float*)d_in[5];
    const float* b1     = (const float*)d_in[6];
    const float* emb    = (const float*)d_in[7];
    const float* W2     = (const float*)d_in[8];
    const float* b2     = (const float*)d_in[9];
    const float* W3     = (const float*)d_in[10];
    const float* b3     = (const float*)d_in[11];
    const int N = in_sizes[3];   // 50000
    const int E = in_sizes[2];   // 800000
    const int* row = ei;
    const int* col = ei + E;
    const int nb = (N + 255) / 256;                 // 196 <= 256
    const int sblocks = (N * (FIN / 4) + 255) / 256;
    const int cblocks = (E + 255) / 256;

    // ws layout (~30.1 MB): partial (1 MB) aliases dead epack region after gather
    unsigned short* w1t    = (unsigned short*)d_ws;                     // 32768 bf16
    unsigned short* xbf    = w1t + (size_t)HID * FIN;                   // N*128 bf16
    unsigned short* xaggbf = xbf + (size_t)N * FIN;                     // N*128 bf16
    unsigned* pk           = (unsigned*)(xaggbf + (size_t)N * FIN);     // N
    unsigned* epack        = pk + N;                                    // E u32
    float* partial         = (float*)epack;                             // 64*16*256 (alias)
    unsigned char* seq     = (unsigned char*)(epack + E);               // E u8
    int*   off    = (int*)(seq + ((E + 3) & ~3));                       // N+1
    int*   bsum   = off + N + 1;                                        // 256
    int*   starts = bsum + 256;                                         // 65

    hipMemsetAsync((void*)pk, 0, (size_t)N * sizeof(unsigned), stream);
    k_setupcount<<<sblocks + cblocks, 256, 0, stream>>>(x, xbf, W1, w1t, col, ew,
                                                        pk, seq, N, E, sblocks);
    k_scanA2<<<nb, 256, 0, stream>>>(pk, off, bsum, N);
    k_scanC2<<<nb, 256, 0, stream>>>(off, bsum, N, nb, batch, starts);
    k_fill<<<(E + 255) / 256, 256, 0, stream>>>(row, col, ew, pk, off, seq, epack, E);
    k_gather<<<(N + 7) / 8, 256, 0, stream>>>(off, epack, xbf, pk, xaggbf, N);
    dim3 pgrid(GTILES, NGRAPH);
    k_gpool<<<pgrid, 256, 0, stream>>>(xaggbf, w1t, b1, starts, partial);
    k_head<<<NGRAPH, 256, 0, stream>>>(partial, starts, emb, labels, W2, b2, W3, b3,
                                       (float*)d_out);
}

// Round 27
// 154.456 us; speedup vs baseline: 1.0132x; 1.0132x over previous
//
#include <hip/hip_runtime.h>

#define HID 256
#define FIN 128
#define NGRAPH 64
#define NEG 0.2f
#define DEGSCALE 16384.0f
#define GTILES 16

typedef __attribute__((ext_vector_type(8))) short short8;
typedef __attribute__((ext_vector_type(4))) float f32x4;

__device__ __forceinline__ float lrelu(float v) { return v >= 0.f ? v : NEG * v; }

__device__ __forceinline__ unsigned short f2bf(float f) {
    union { float f; unsigned u; } c; c.f = f;
    unsigned u = c.u;
    unsigned r = (u + 0x7FFFu + ((u >> 16) & 1u)) >> 16;   // RNE
    return (unsigned short)r;
}
__device__ __forceinline__ float bf2f(unsigned short u) {
    union { unsigned u; float f; } c; c.u = ((unsigned)u) << 16; return c.f;
}

// ---------------- fused setup: cvtX + cvtW1 + init (validated round 23/24) ----------------

__global__ void k_setup(const float* __restrict__ x, unsigned short* __restrict__ xbf,
                        const float* __restrict__ W1, unsigned short* __restrict__ w1t,
                        unsigned* __restrict__ pk, int N) {
    int i = blockIdx.x * 256 + threadIdx.x;
    int n4 = N * (FIN / 4);
    if (i < n4) {
        float4 v = ((const float4*)x)[i];
        ushort4 o; o.x = f2bf(v.x); o.y = f2bf(v.y); o.z = f2bf(v.z); o.w = f2bf(v.w);
        ((ushort4*)xbf)[i] = o;
    }
    if (i < FIN * HID) {
        int k = i >> 8;
        int n = i & 255;
        w1t[(size_t)n * FIN + k] = f2bf(W1[(size_t)k * HID + n]);
    }
    if (i < N) pk[i] = (unsigned)(1.0f * DEGSCALE);
}

// ---------------- count (validated round 22) ----------------

__global__ void k_count(const int* __restrict__ col, const float* __restrict__ ew,
                        unsigned* __restrict__ pk, unsigned char* __restrict__ seq, int E) {
    int e = blockIdx.x * 256 + threadIdx.x;
    if (e < E) {
        unsigned fixw = (unsigned)(ew[e] * DEGSCALE + 0.5f);
        unsigned old = atomicAdd(&pk[col[e]], (1u << 24) | fixw);
        seq[e] = (unsigned char)(old >> 24);
    }
}

// ---------------- fused dinv + scanA (validated round 23) ----------------

__global__ void k_scanA2(unsigned* __restrict__ pk, int* __restrict__ off,
                         int* __restrict__ bsum, int N) {
    __shared__ int buf[256];
    int t = threadIdx.x, i = blockIdx.x * 256 + t;
    unsigned p = (i < N) ? pk[i] : 0u;
    buf[t] = (int)(p >> 24);
    __syncthreads();
    for (int s = 1; s < 256; s <<= 1) {
        int a = (t >= s) ? buf[t - s] : 0;
        __syncthreads();
        buf[t] += a;
        __syncthreads();
    }
    if (i < N) {
        off[i + 1] = buf[t];
        float dg = (float)(p & 0xFFFFFFu) * (1.0f / DEGSCALE);
        float dv = dg > 0.f ? rsqrtf(dg) : 0.f;
        union { float f; unsigned u; } c; c.f = dv;
        pk[i] = c.u;
    }
    if (t == 255) bsum[blockIdx.x] = buf[255];
}

// ---------------- fused scanB + scanC + starts (validated round 23) ----------------

__global__ void k_scanC2(int* __restrict__ off, const int* __restrict__ bsum, int N, int nb,
                         const int* __restrict__ batch, int* __restrict__ starts) {
    __shared__ int sb[256];
    int t = threadIdx.x;
    sb[t] = (t < nb) ? bsum[t] : 0;
    __syncthreads();
    for (int s = 1; s < 256; s <<= 1) {
        int a = (t >= s) ? sb[t - s] : 0;
        __syncthreads();
        sb[t] += a;
        __syncthreads();
    }
    int i = blockIdx.x * 256 + t;
    if (i < N && blockIdx.x > 0) off[i + 1] += sb[blockIdx.x - 1];
    if (i == 0) off[0] = 0;
    if (blockIdx.x == 0 && t <= NGRAPH) {
        int g = t;
        int lo = 0, hi = N;
        while (lo < hi) {
            int mid = (lo + hi) >> 1;
            if (batch[mid] < g) lo = mid + 1; else hi = mid;
        }
        starts[g] = lo;
    }
}

// ---------------- fill (validated round 22) ----------------

__global__ void k_fill(const int* __restrict__ row, const int* __restrict__ col,
                       const float* __restrict__ ew, const unsigned* __restrict__ dinvu,
                       const int* __restrict__ off, const unsigned char* __restrict__ seq,
                       unsigned* __restrict__ epack, int E) {
    int e = blockIdx.x * 256 + threadIdx.x;
    if (e >= E) return;
    int r = row[e], c = col[e];
    union { unsigned u; float f; } dr, dc;
    dr.u = dinvu[r]; dc.u = dinvu[c];
    float w = dr.f * ew[e] * dc.f;
    int s = off[c] + (int)seq[e];
    epack[s] = ((unsigned)f2bf(w) << 16) | (unsigned)r;
}

// ---------------- gather v4 (validated round 24): 4-way unroll ----------------

__global__ __launch_bounds__(256) void k_gather(const int* __restrict__ off,
        const unsigned* __restrict__ epack,
        const unsigned short* __restrict__ xbf, const unsigned* __restrict__ dinvu,
        unsigned short* __restrict__ xaggbf, int N) {
    int n = blockIdx.x * 8 + (threadIdx.x >> 5);
    int l = threadIdx.x & 31;
    if (n >= N) return;
    const ushort4* x4 = (const ushort4*)xbf;
    union { unsigned u; float f; } dc; dc.u = dinvu[n];
    float s2 = dc.f * dc.f;
    ushort4 xv = x4[(size_t)n * 32 + l];
    float ax = s2 * bf2f(xv.x), ay = s2 * bf2f(xv.y), az = s2 * bf2f(xv.z), aw = s2 * bf2f(xv.w);
    float bx = 0.f, by = 0.f, bz = 0.f, bw = 0.f;
    float cx = 0.f, cy = 0.f, cz = 0.f, cw = 0.f;
    float dx = 0.f, dy = 0.f, dz = 0.f, dw = 0.f;
    int s0 = off[n], s1 = off[n + 1];
    int s = s0;
    for (; s + 4 <= s1; s += 4) {
        unsigned p0 = epack[s],     p1 = epack[s + 1];
        unsigned p2 = epack[s + 2], p3 = epack[s + 3];
        float w0 = bf2f((unsigned short)(p0 >> 16));
        float w1 = bf2f((unsigned short)(p1 >> 16));
        float w2 = bf2f((unsigned short)(p2 >> 16));
        float w3 = bf2f((unsigned short)(p3 >> 16));
        ushort4 v0 = x4[(size_t)(p0 & 0xFFFFu) * 32 + l];
        ushort4 v1 = x4[(size_t)(p1 & 0xFFFFu) * 32 + l];
        ushort4 v2 = x4[(size_t)(p2 & 0xFFFFu) * 32 + l];
        ushort4 v3 = x4[(size_t)(p3 & 0xFFFFu) * 32 + l];
        ax += w0 * bf2f(v0.x); ay += w0 * bf2f(v0.y); az += w0 * bf2f(v0.z); aw += w0 * bf2f(v0.w);
        bx += w1 * bf2f(v1.x); by += w1 * bf2f(v1.y); bz += w1 * bf2f(v1.z); bw += w1 * bf2f(v1.w);
        cx += w2 * bf2f(v2.x); cy += w2 * bf2f(v2.y); cz += w2 * bf2f(v2.z); cw += w2 * bf2f(v2.w);
        dx += w3 * bf2f(v3.x); dy += w3 * bf2f(v3.y); dz += w3 * bf2f(v3.z); dw += w3 * bf2f(v3.w);
    }
    for (; s < s1; ++s) {
        unsigned p0 = epack[s];
        float w0 = bf2f((unsigned short)(p0 >> 16));
        ushort4 v0 = x4[(size_t)(p0 & 0xFFFFu) * 32 + l];
        ax += w0 * bf2f(v0.x); ay += w0 * bf2f(v0.y); az += w0 * bf2f(v0.z); aw += w0 * bf2f(v0.w);
    }
    ushort4 st;
    st.x = f2bf((ax + bx) + (cx + dx));
    st.y = f2bf((ay + by) + (cy + dy));
    st.z = f2bf((az + bz) + (cz + dz));
    st.w = f2bf((aw + bw) + (cw + dw));
    ((ushort4*)xaggbf)[(size_t)n * 32 + l] = st;
}

// ---------------- gpool v10 (validated round 24) ----------------

__global__ __launch_bounds__(256) void k_gpool(
        const unsigned short* __restrict__ xaggbf, const unsigned short* __restrict__ w1t,
        const float* __restrict__ b1, const int* __restrict__ starts,
        float* __restrict__ partial) {
    __shared__ float red[4][128];
    const int tile = blockIdx.x;
    const int g = blockIdx.y;
    const int t = threadIdx.x;
    const int w = t >> 6;
    const int l = t & 63;
    const int col = l & 15;
    const int koff = (l >> 4) * 8;
    const int gs = starts[g], ge = starts[g + 1];
    const int n0 = gs + tile * 64;
    float* pbase = partial + ((size_t)g * GTILES + tile) * HID;
    if (n0 >= ge) {
        pbase[t] = 0.f;
        return;
    }
    int rbase = n0 + w * 16 + col;
    int rclamp = rbase < ge ? rbase : ge - 1;
    short8 a[4];
    #pragma unroll
    for (int kt = 0; kt < 4; ++kt)
        a[kt] = *(const short8*)(xaggbf + (size_t)rclamp * FIN + kt * 32 + koff);
    const int rowbase = n0 + w * 16 + (l >> 4) * 4;
    #pragma unroll
    for (int half = 0; half < 2; ++half) {
        const int col0 = half * 128;
        f32x4 acc[8];
        #pragma unroll
        for (int c = 0; c < 8; ++c) acc[c] = (f32x4){0.f, 0.f, 0.f, 0.f};
        #pragma unroll
        for (int kt = 0; kt < 4; ++kt) {
            short8 b[8];
            #pragma unroll
            for (int c = 0; c < 8; ++c)
                b[c] = *(const short8*)(w1t + (size_t)(col0 + c * 16 + col) * FIN + kt * 32 + koff);
            #pragma unroll
            for (int c = 0; c < 8; ++c)
                acc[c] = __builtin_amdgcn_mfma_f32_16x16x32_bf16(a[kt], b[c], acc[c], 0, 0, 0);
        }
        if (half) __syncthreads();
        #pragma unroll
        for (int c = 0; c < 8; ++c) {
            float bias = b1[col0 + c * 16 + col];
            float s = 0.f;
            #pragma unroll
            for (int r = 0; r < 4; ++r)
                if (rowbase + r < ge) s += lrelu(acc[c][r] + bias);
            s += __shfl_xor(s, 16);
            s += __shfl_xor(s, 32);
            if (l < 16) red[w][c * 16 + l] = s;
        }
        __syncthreads();
        if (t < 128) pbase[col0 + t] = red[0][t] + red[1][t] + red[2][t] + red[3][t];
    }
}

// ---------------- head (validated round 21) ----------------

__global__ void k_head(const float* __restrict__ partial, const int* __restrict__ starts,
                       const float* __restrict__ emb, const int* __restrict__ labels,
                       const float* __restrict__ W2, const float* __restrict__ b2,
                       const float* __restrict__ W3, const float* __restrict__ b3,
                       float* __restrict__ out) {
    __shared__ float z[384];
    __shared__ float red[256];
    int g = blockIdx.x, t = threadIdx.x;
    int cnt = starts[g + 1] - starts[g];
    float inv = 1.0f / (float)(cnt < 1 ? 1 : cnt);
    float s = 0.f;
    #pragma unroll
    for (int i = 0; i < GTILES; ++i)
        s += partial[((size_t)g * GTILES + i) * HID + t];
    z[t] = s * inv;
    if (t < 128) z[HID + t] = emb[labels[g] * 128 + t];
    __syncthreads();
    float acc = b2[t];
    for (int k = 0; k < 384; ++k) acc += z[k] * W2[k * HID + t];
    red[t] = lrelu(acc) * W3[t];
    __syncthreads();
    for (int ss = 128; ss > 0; ss >>= 1) {
        if (t < ss) red[t] += red[t + ss];
        __syncthreads();
    }
    if (t == 0) out[g] = red[0] + b3[0];
}

extern "C" void kernel_launch(void* const* d_in, const int* in_sizes, int n_in,
                              void* d_out, int out_size, void* d_ws, size_t ws_size,
                              hipStream_t stream) {
    (void)n_in; (void)out_size; (void)ws_size;
    const float* x      = (const float*)d_in[0];
    const int*   ei     = (const int*)d_in[1];
    const float* ew     = (const float*)d_in[2];
    const int*   batch  = (const int*)d_in[3];
    const int*   labels = (const int*)d_in[4];
    const float* W1     = (const float*)d_in[5];
    const float* b1     = (const float*)d_in[6];
    const float* emb    = (const float*)d_in[7];
    const float* W2     = (const float*)d_in[8];
    const float* b2     = (const float*)d_in[9];
    const float* W3     = (const float*)d_in[10];
    const float* b3     = (const float*)d_in[11];
    const int N = in_sizes[3];   // 50000
    const int E = in_sizes[2];   // 800000
    const int* row = ei;
    const int* col = ei + E;
    const int nb = (N + 255) / 256;   // 196 <= 256

    // ws layout (~30.1 MB): partial (1 MB) aliases dead epack region after gather
    unsigned short* w1t    = (unsigned short*)d_ws;                     // 32768 bf16
    unsigned short* xbf    = w1t + (size_t)HID * FIN;                   // N*128 bf16
    unsigned short* xaggbf = xbf + (size_t)N * FIN;                     // N*128 bf16
    unsigned* pk           = (unsigned*)(xaggbf + (size_t)N * FIN);     // N
    unsigned* epack        = pk + N;                                    // E u32
    float* partial         = (float*)epack;                             // 64*16*256 (alias)
    unsigned char* seq     = (unsigned char*)(epack + E);               // E u8
    int*   off    = (int*)(seq + ((E + 3) & ~3));                       // N+1
    int*   bsum   = off + N + 1;                                        // 256
    int*   starts = bsum + 256;                                         // 65

    k_setup<<<(N * (FIN / 4) + 255) / 256, 256, 0, stream>>>(x, xbf, W1, w1t, pk, N);
    k_count<<<(E + 255) / 256, 256, 0, stream>>>(col, ew, pk, seq, E);
    k_scanA2<<<nb, 256, 0, stream>>>(pk, off, bsum, N);
    k_scanC2<<<nb, 256, 0, stream>>>(off, bsum, N, nb, batch, starts);
    k_fill<<<(E + 255) / 256, 256, 0, stream>>>(row, col, ew, pk, off, seq, epack, E);
    k_gather<<<(N + 7) / 8, 256, 0, stream>>>(off, epack, xbf, pk, xaggbf, N);
    dim3 pgrid(GTILES, NGRAPH);
    k_gpool<<<pgrid, 256, 0, stream>>>(xaggbf, w1t, b1, starts, partial);
    k_head<<<NGRAPH, 256, 0, stream>>>(partial, starts, emb, labels, W2, b2, W3, b3,
                                       (float*)d_out);
}